// Round 5
// baseline (286.716 us; speedup 1.0000x reference)
//
#include <hip/hip_runtime.h>
#include <stdint.h>

#define NSAMP 1024
#define D 16384
#define WH 128
#define MARGIN 0.3f
#define KS 8
#define KSUB (D / KS)
#define SCALE 0.08838834764831845f    // 1/sqrt(128)
#define RSCALE 11.313708498984761f    // sqrt(128)

typedef unsigned int uint;
typedef unsigned short ushort_t;

typedef __attribute__((ext_vector_type(8))) short bf16x8;   // 8 bf16 = 4 VGPRs
typedef __attribute__((ext_vector_type(4))) float f32x4;

__device__ __forceinline__ float bf2f(unsigned short b) {
    return __uint_as_float(((uint)b) << 16);
}
__device__ __forceinline__ unsigned short f2bf(float f) {
    uint u = __float_as_uint(f);
    u += 0x7fffu + ((u >> 16) & 1u);   // RNE (data has no NaN)
    return (unsigned short)(u >> 16);
}
__device__ __forceinline__ void gload_lds16(const void* g, void* l) {
    __builtin_amdgcn_global_load_lds(
        (const __attribute__((address_space(1))) uint32_t*)g,
        (__attribute__((address_space(3))) uint32_t*)l, 16, 0, 0);
}
// Halve all 8 bf16 lanes: exponent-field decrement (exact; hi-split of N(0,1)
// data is never subnormal/zero, so no borrow).
__device__ __forceinline__ bf16x8 bf8_half(bf16x8 v) {
    union { bf16x8 b; uint u[4]; } c;
    c.b = v;
    c.u[0] -= 0x00800080u; c.u[1] -= 0x00800080u;
    c.u[2] -= 0x00800080u; c.u[3] -= 0x00800080u;
    return c.b;
}
// Swizzled LDS byte offset for a 128-col bf16 row-major tile.
__device__ __forceinline__ int lds_off(int row, int col) {
    return row * 256 + ((((col >> 3) ^ (row & 15)) << 4) | ((col & 7) << 1));
}

// ---------------- kernel 1: row norms + hi/lo bf16 split ----------------
__global__ __launch_bounds__(256) void k_norms_split(const float* __restrict__ x,
                                                     float* __restrict__ sq,
                                                     ushort_t* __restrict__ xhi,
                                                     ushort_t* __restrict__ xlo) {
    int b = blockIdx.x;
    int tid = threadIdx.x;
    const float* xr = x + (size_t)b * D;
    ushort_t* hr = xhi + (size_t)b * D;
    ushort_t* lr = xlo + (size_t)b * D;
    float s = 0.f;
    #pragma unroll
    for (int m = 0; m < 16; ++m) {
        int e = m * 1024 + tid * 4;
        float4 v = *(const float4*)(xr + e);
        s += v.x * v.x + v.y * v.y + v.z * v.z + v.w * v.w;
        ushort4 h, l;
        h.x = f2bf(v.x); l.x = f2bf(v.x - bf2f(h.x));
        h.y = f2bf(v.y); l.y = f2bf(v.y - bf2f(h.y));
        h.z = f2bf(v.z); l.z = f2bf(v.z - bf2f(h.z));
        h.w = f2bf(v.w); l.w = f2bf(v.w - bf2f(h.w));
        *(ushort4*)(hr + e) = h;
        *(ushort4*)(lr + e) = l;
    }
    for (int off = 32; off; off >>= 1) s += __shfl_down(s, off, 64);
    __shared__ float red[4];
    if ((tid & 63) == 0) red[tid >> 6] = s;
    __syncthreads();
    if (tid == 0) sq[b] = red[0] + red[1] + red[2] + red[3];
}

// ---------------- kernel 2: GB = 0.5*Hi.Hi^T + Hi.Lo^T via MFMA ----------------
// XCD swizzle: ks = lin&7 pins each K-slice (8 MB working set) to one XCD's L2;
// bi sweeps next so B-tiles are reused across consecutive same-XCD blocks.
__global__ __launch_bounds__(256) void k_gram_mfma(const ushort_t* __restrict__ xhi,
                                                   const ushort_t* __restrict__ xlo,
                                                   float* __restrict__ Gp) {
    int lin = blockIdx.x + 8 * blockIdx.y + 64 * blockIdx.z;
    int ks = lin & 7, bi = (lin >> 3) & 7, bj = lin >> 6;
    int i0 = bi * 128, j0 = bj * 128;
    int tid = threadIdx.x;
    int w = tid >> 6, lane = tid & 63;
    int wm = w & 1, wn = w >> 1;
    int quad = lane >> 4, m16 = lane & 15;
    int srow = lane >> 2, sseg = lane & 3;

    __shared__ __align__(16) ushort_t Ahi_s[128 * 32];
    __shared__ __align__(16) ushort_t Bhi_s[128 * 32];
    __shared__ __align__(16) ushort_t Blo_s[128 * 32];

    f32x4 acc[4][4];
    #pragma unroll
    for (int ii = 0; ii < 4; ++ii)
        #pragma unroll
        for (int jj = 0; jj < 4; ++jj)
            acc[ii][jj] = (f32x4){0.f, 0.f, 0.f, 0.f};

    const size_t Abase = (size_t)i0 * D;
    const size_t Bbase = (size_t)j0 * D;

    for (int kb = 0; kb < KSUB / 32; ++kb) {
        int k0 = ks * KSUB + kb * 32;
        #pragma unroll
        for (int c = 0; c < 2; ++c) {
            int r = w * 32 + c * 16 + srow;
            size_t go = (size_t)r * D + k0 + sseg * 8;
            int lo = (w * 32 + c * 16) * 32;
            gload_lds16(xhi + Abase + go, &Ahi_s[lo]);
            gload_lds16(xhi + Bbase + go, &Bhi_s[lo]);
            gload_lds16(xlo + Bbase + go, &Blo_s[lo]);
        }
        __syncthreads();

        bf16x8 ah[4], bh[4], bl[4];
        #pragma unroll
        for (int ii = 0; ii < 4; ++ii) {
            int ar = wm * 64 + ii * 16 + m16;
            ah[ii] = *(const bf16x8*)&Ahi_s[ar * 32 + quad * 8];
        }
        #pragma unroll
        for (int jj = 0; jj < 4; ++jj) {
            int br = wn * 64 + jj * 16 + m16;
            bh[jj] = *(const bf16x8*)&Bhi_s[br * 32 + quad * 8];
            bl[jj] = *(const bf16x8*)&Blo_s[br * 32 + quad * 8];
        }
        #pragma unroll
        for (int ii = 0; ii < 4; ++ii) {
            bf16x8 ahh = bf8_half(ah[ii]);
            #pragma unroll
            for (int jj = 0; jj < 4; ++jj) {
                acc[ii][jj] = __builtin_amdgcn_mfma_f32_16x16x32_bf16(ahh, bh[jj], acc[ii][jj], 0, 0, 0);
                acc[ii][jj] = __builtin_amdgcn_mfma_f32_16x16x32_bf16(ah[ii], bl[jj], acc[ii][jj], 0, 0, 0);
            }
        }
        __syncthreads();
    }

    float* Gb = Gp + (size_t)ks * NSAMP * NSAMP;
    #pragma unroll
    for (int ii = 0; ii < 4; ++ii)
        #pragma unroll
        for (int jj = 0; jj < 4; ++jj) {
            int rg = i0 + wm * 64 + ii * 16 + quad * 4;
            int cg = j0 + wn * 64 + jj * 16 + m16;
            #pragma unroll
            for (int r = 0; r < 4; ++r)
                Gb[(size_t)(rg + r) * NSAMP + cg] = acc[ii][jj][r];
        }
}

// ---------------- kernel 2b: fold the KS partials -> Gsum ----------------
__global__ __launch_bounds__(256) void k_fold(const float* __restrict__ Gp,
                                              float* __restrict__ Gsum) {
    size_t idx = ((size_t)blockIdx.x * 256 + threadIdx.x) * 4;
    float4 s = *(const float4*)(Gp + idx);
    #pragma unroll
    for (int p = 1; p < KS; ++p) {
        float4 v = *(const float4*)(Gp + (size_t)p * NSAMP * NSAMP + idx);
        s.x += v.x; s.y += v.y; s.z += v.z; s.w += v.w;
    }
    *(float4*)(Gsum + idx) = s;
}

// ---------------- kernel 2c: per-sample 128x128 transpose of xhi -> xhiT ----
__global__ __launch_bounds__(256) void k_transpose(const ushort_t* __restrict__ xhi,
                                                   ushort_t* __restrict__ xhiT) {
    int b = blockIdx.x;
    int tid = threadIdx.x;
    __shared__ __align__(16) char sm[65536];   // [0,32K) rows; [32K,64K) transposed
    const ushort_t* src = xhi + (size_t)b * D;
    ushort_t* dst = xhiT + (size_t)b * D;

    uint4 stg[8];
    #pragma unroll
    for (int k = 0; k < 8; ++k)
        stg[k] = *(const uint4*)(src + (size_t)(tid + 256 * k) * 8);
    #pragma unroll
    for (int k = 0; k < 8; ++k) {
        int g = tid + 256 * k;
        *(uint4*)(sm + lds_off(g >> 4, (g & 15) * 8)) = stg[k];
    }
    __syncthreads();

    int r0 = (tid & 31) * 4, h0 = (tid >> 5) * 16;
    uint4 trd[4][2];
    #pragma unroll
    for (int j = 0; j < 4; ++j)
        #pragma unroll
        for (int k = 0; k < 2; ++k)
            trd[j][k] = *(const uint4*)(sm + lds_off(r0 + j, h0 + 8 * k));
    #pragma unroll
    for (int i = 0; i < 16; ++i) {
        uint v[4];
        #pragma unroll
        for (int j = 0; j < 4; ++j) {
            uint wo = ((const uint*)&trd[j][i >> 3])[(i >> 1) & 3];
            v[j] = (i & 1) ? (wo >> 16) : (wo & 0xffffu);
        }
        uint2 pk;
        pk.x = v[0] | (v[1] << 16);
        pk.y = v[2] | (v[3] << 16);
        *(uint2*)(sm + 32768 + lds_off(h0 + i, r0)) = pk;
    }
    __syncthreads();

    #pragma unroll
    for (int k = 0; k < 8; ++k) {
        int g = tid + 256 * k;
        uint4 v = *(const uint4*)(sm + 32768 + lds_off(g >> 4, (g & 15) * 8));
        *(uint4*)(dst + (size_t)g * 8) = v;
    }
}

// ---------------- kernel 3: hardest pos/neg + dsq init ----------------
__global__ void k_select(const float* __restrict__ Gsum,
                         const float* __restrict__ sq, const int* __restrict__ tgt,
                         int* __restrict__ hp, int* __restrict__ hn,
                         float* __restrict__ dsq) {
    int i = blockIdx.x;
    int tid = threadIdx.x;
    float sqi = sq[i];
    int ti = tgt[i];
    float pv = -3.0e38f; int pj = 0x7FFFFFFF;
    float nv = 3.0e38f;  int nj = 0x7FFFFFFF;
    #pragma unroll
    for (int m = 0; m < 4; ++m) {
        int j = tid + 256 * m;
        float g = Gsum[(size_t)i * NSAMP + j] + Gsum[(size_t)j * NSAMP + i];
        float d2 = sqi + sq[j] - 2.f * g;
        float d = sqrtf(fmaxf(d2, 1e-12f));
        bool same = (tgt[j] == ti);
        float cp = same ? d : -1e30f;
        float cn = same ? 1e30f : d;
        if (cp > pv || (cp == pv && j < pj)) { pv = cp; pj = j; }
        if (cn < nv || (cn == nv && j < nj)) { nv = cn; nj = j; }
    }
    for (int off = 32; off; off >>= 1) {
        float opv = __shfl_down(pv, off, 64); int opj = __shfl_down(pj, off, 64);
        float onv = __shfl_down(nv, off, 64); int onj = __shfl_down(nj, off, 64);
        if (opv > pv || (opv == pv && opj < pj)) { pv = opv; pj = opj; }
        if (onv < nv || (onv == nv && onj < nj)) { nv = onv; nj = onj; }
    }
    __shared__ float spv[4], snv[4];
    __shared__ int spj[4], snj[4];
    if ((tid & 63) == 0) { int wv = tid >> 6; spv[wv] = pv; spj[wv] = pj; snv[wv] = nv; snj[wv] = nj; }
    __syncthreads();
    if (tid == 0) {
        for (int wv = 1; wv < 4; ++wv) {
            if (spv[wv] > pv || (spv[wv] == pv && spj[wv] < pj)) { pv = spv[wv]; pj = spj[wv]; }
            if (snv[wv] < nv || (snv[wv] == nv && snj[wv] < nj)) { nv = snv[wv]; nj = snj[wv]; }
        }
        hp[i] = pj; hn[i] = nj;
        // dsq = ||A||^2 init; k_dc adds (-2*Tr(A.M) + ||M||^2)
        dsq[i] = sqi; dsq[NSAMP + i] = sqi;
    }
}

// ---------------- kernel 4: DC align, barrier-free MFMA ----------------
// grid (b=1024, which=2), 4 waves. All fragments direct from global (L3-warm);
// P is wave-private LDS (8 KB/wave); zero __syncthreads.
__global__ __launch_bounds__(256) void k_dc_mfma(const ushort_t* __restrict__ xhi,
                                                 const ushort_t* __restrict__ xhiT,
                                                 const int* __restrict__ hp,
                                                 const int* __restrict__ hn,
                                                 float* __restrict__ dsq) {
    int b = blockIdx.x;
    int which = blockIdx.y;
    int oidx = (which == 0) ? hp[b] : hn[b];
    const ushort_t* Ag = xhi + (size_t)b * D;
    const ushort_t* Og = xhi + (size_t)oidx * D;
    const ushort_t* OTg = xhiT + (size_t)oidx * D;

    __shared__ __align__(16) char smem[32768];   // 4 waves x 8KB wave-private P

    int tid = threadIdx.x;
    int wv = tid >> 6, lane = tid & 63;
    int quad = lane >> 4, m16 = lane & 15;
    char* Pb = smem + wv * 8192;

    // ---- S^T pass: accS[ti][tj2] = MFMA(O-rows, A-rows); all frags global ----
    f32x4 accS[8][2];
    #pragma unroll
    for (int ti = 0; ti < 8; ++ti)
        #pragma unroll
        for (int tj2 = 0; tj2 < 2; ++tj2)
            accS[ti][tj2] = (f32x4){0.f, 0.f, 0.f, 0.f};
    #pragma unroll
    for (int ks = 0; ks < 4; ++ks) {
        int kc = ks * 32 + quad * 8;
        bf16x8 af[2];
        #pragma unroll
        for (int tj2 = 0; tj2 < 2; ++tj2)
            af[tj2] = *(const bf16x8*)(Ag + ((2 * wv + tj2) * 16 + m16) * WH + kc);
        bf16x8 of[8];
        #pragma unroll
        for (int ti = 0; ti < 8; ++ti)
            of[ti] = *(const bf16x8*)(Og + (ti * 16 + m16) * WH + kc);
        #pragma unroll
        for (int ti = 0; ti < 8; ++ti)
            #pragma unroll
            for (int tj2 = 0; tj2 < 2; ++tj2)
                accS[ti][tj2] = __builtin_amdgcn_mfma_f32_16x16x32_bf16(of[ti], af[tj2], accS[ti][tj2], 0, 0, 0);
    }

    // ---- softmax over c (in-lane + quad shuffles); single exp; P -> LDS ----
    float tpart = 0.f;
    #pragma unroll
    for (int tj2 = 0; tj2 < 2; ++tj2) {
        float mx = -3.0e38f;
        #pragma unroll
        for (int ti = 0; ti < 8; ++ti)
            #pragma unroll
            for (int r = 0; r < 4; ++r) {
                float s = accS[ti][tj2][r] * SCALE;
                accS[ti][tj2][r] = s;
                mx = fmaxf(mx, s);
            }
        mx = fmaxf(mx, __shfl_xor(mx, 16, 64));
        mx = fmaxf(mx, __shfl_xor(mx, 32, 64));
        float sum = 0.f, tnum = 0.f;
        #pragma unroll
        for (int ti = 0; ti < 8; ++ti)
            #pragma unroll
            for (int r = 0; r < 4; ++r) {
                float s = accS[ti][tj2][r];
                float e = __expf(s - mx);
                accS[ti][tj2][r] = e;      // s consumed into tnum
                sum += e;
                tnum += s * e;
            }
        sum += __shfl_xor(sum, 16, 64);
        sum += __shfl_xor(sum, 32, 64);
        tnum += __shfl_xor(tnum, 16, 64);
        tnum += __shfl_xor(tnum, 32, 64);
        float inv = 1.f / sum;
        tpart += 0.25f * tnum * inv;       // each of 4 quads adds the full row sum
        int rloc = tj2 * 16 + m16;
        #pragma unroll
        for (int ti = 0; ti < 8; ++ti) {
            uint pk0, pk1;
            {
                unsigned short p0 = f2bf(accS[ti][tj2][0] * inv);
                unsigned short p1 = f2bf(accS[ti][tj2][1] * inv);
                unsigned short p2 = f2bf(accS[ti][tj2][2] * inv);
                unsigned short p3 = f2bf(accS[ti][tj2][3] * inv);
                pk0 = (uint)p0 | ((uint)p1 << 16);
                pk1 = (uint)p2 | ((uint)p3 << 16);
            }
            *(uint2*)(Pb + lds_off(rloc, ti * 16 + quad * 4)) = make_uint2(pk0, pk1);
        }
    }

    // ---- M pass: M = P . O via MFMA(P from wave-private LDS, Ot rows global) ----
    f32x4 accM[2][8];
    #pragma unroll
    for (int tj2 = 0; tj2 < 2; ++tj2)
        #pragma unroll
        for (int tj = 0; tj < 8; ++tj)
            accM[tj2][tj] = (f32x4){0.f, 0.f, 0.f, 0.f};
    #pragma unroll
    for (int ks = 0; ks < 4; ++ks) {
        int kc = ks * 32 + quad * 8;
        bf16x8 pfr[2];
        #pragma unroll
        for (int tj2 = 0; tj2 < 2; ++tj2)
            pfr[tj2] = *(const bf16x8*)(Pb + lds_off(tj2 * 16 + m16, (ks * 4 + quad) * 8));
        bf16x8 otf[8];
        #pragma unroll
        for (int tj = 0; tj < 8; ++tj)
            otf[tj] = *(const bf16x8*)(OTg + (tj * 16 + m16) * WH + kc);
        #pragma unroll
        for (int tj2 = 0; tj2 < 2; ++tj2)
            #pragma unroll
            for (int tj = 0; tj < 8; ++tj)
                accM[tj2][tj] = __builtin_amdgcn_mfma_f32_16x16x32_bf16(pfr[tj2], otf[tj], accM[tj2][tj], 0, 0, 0);
    }

    float m2 = 0.f;
    #pragma unroll
    for (int tj2 = 0; tj2 < 2; ++tj2)
        #pragma unroll
        for (int tj = 0; tj < 8; ++tj)
            #pragma unroll
            for (int r = 0; r < 4; ++r) {
                float mvv = accM[tj2][tj][r];
                m2 += mvv * mvv;
            }
    float part = m2 - 2.f * RSCALE * tpart;
    for (int off = 32; off; off >>= 1) part += __shfl_down(part, off, 64);
    if (lane == 0) atomicAdd(&dsq[which * NSAMP + b], part);
}

// ---------------- kernel 5: final loss ----------------
__global__ void k_loss(const float* __restrict__ dsq, float* __restrict__ out) {
    int tid = threadIdx.x;
    float s = 0.f;
    #pragma unroll
    for (int m = 0; m < 4; ++m) {
        int b = tid + 256 * m;
        float ap = sqrtf(fmaxf(dsq[b], 0.f));
        float an = sqrtf(fmaxf(dsq[NSAMP + b], 0.f));
        s += fmaxf(ap - an + MARGIN, 0.f);
    }
    for (int off = 32; off; off >>= 1) s += __shfl_down(s, off, 64);
    __shared__ float red[4];
    if ((tid & 63) == 0) red[tid >> 6] = s;
    __syncthreads();
    if (tid == 0) out[0] = (red[0] + red[1] + red[2] + red[3]) * (1.f / NSAMP);
}

extern "C" void kernel_launch(void* const* d_in, const int* in_sizes, int n_in,
                              void* d_out, int out_size, void* d_ws, size_t ws_size,
                              hipStream_t stream) {
    const float* x = (const float*)d_in[0];
    const int* tgt = (const int*)d_in[1];
    float* out = (float*)d_out;
    char* ws = (char*)d_ws;

    float* Gp = (float*)ws;                                       // KS * 4 MB = 32 MB
    ushort_t* xhiT = (ushort_t*)ws;                               // 32 MB, reuses Gp after k_fold
    ushort_t* xhi = (ushort_t*)(ws + (size_t)32 * 1024 * 1024);   // 32 MB
    ushort_t* xlo = xhi + (size_t)NSAMP * D;                      // 32 MB (dead after gram)
    float* Gsum = (float*)xlo;                                    // 4 MB, overlaps xlo
    float* sq = (float*)(ws + (size_t)96 * 1024 * 1024);          // 4 KB
    float* dsq = sq + NSAMP;                                      // 8 KB
    int* hp = (int*)(dsq + 2 * NSAMP);                            // 4 KB
    int* hn = hp + NSAMP;                                         // 4 KB

    k_norms_split<<<NSAMP, 256, 0, stream>>>(x, sq, xhi, xlo);
    k_gram_mfma<<<dim3(8, 8, 8), 256, 0, stream>>>(xhi, xlo, Gp);
    k_fold<<<NSAMP, 256, 0, stream>>>(Gp, Gsum);
    k_transpose<<<NSAMP, 256, 0, stream>>>(xhi, xhiT);            // Gp dead now
    k_select<<<NSAMP, 256, 0, stream>>>(Gsum, sq, tgt, hp, hn, dsq);
    k_dc_mfma<<<dim3(NSAMP, 2), 256, 0, stream>>>(xhi, xhiT, hp, hn, dsq);
    k_loss<<<1, 256, 0, stream>>>(dsq, out);
}

// Round 6
// 233.320 us; speedup vs baseline: 1.2289x; 1.2289x over previous
//
#include <hip/hip_runtime.h>
#include <stdint.h>

#define NSAMP 1024
#define D 16384
#define WH 128
#define MARGIN 0.3f
#define KS 8
#define KSUB (D / KS)
#define SCALE 0.08838834764831845f    // 1/sqrt(128)
#define RSCALE 11.313708498984761f    // sqrt(128)

typedef unsigned int uint;
typedef unsigned short ushort_t;

typedef __attribute__((ext_vector_type(8))) short bf16x8;   // 8 bf16 = 4 VGPRs
typedef __attribute__((ext_vector_type(4))) float f32x4;

__device__ __forceinline__ float bf2f(unsigned short b) {
    return __uint_as_float(((uint)b) << 16);
}
__device__ __forceinline__ unsigned short f2bf(float f) {
    uint u = __float_as_uint(f);
    u += 0x7fffu + ((u >> 16) & 1u);   // RNE (data has no NaN)
    return (unsigned short)(u >> 16);
}
__device__ __forceinline__ void gload_lds16(const void* g, void* l) {
    __builtin_amdgcn_global_load_lds(
        (const __attribute__((address_space(1))) uint32_t*)g,
        (__attribute__((address_space(3))) uint32_t*)l, 16, 0, 0);
}
// Halve all 8 bf16 lanes: exponent-field decrement (exact; hi-split of N(0,1)
// data is never subnormal/zero, so no borrow).
__device__ __forceinline__ bf16x8 bf8_half(bf16x8 v) {
    union { bf16x8 b; uint u[4]; } c;
    c.b = v;
    c.u[0] -= 0x00800080u; c.u[1] -= 0x00800080u;
    c.u[2] -= 0x00800080u; c.u[3] -= 0x00800080u;
    return c.b;
}
// Swizzled LDS byte offset for a 128-col bf16 row-major tile.
__device__ __forceinline__ int lds_off(int row, int col) {
    return row * 256 + ((((col >> 3) ^ (row & 15)) << 4) | ((col & 7) << 1));
}

// ---------------- kernel 1: row norms + hi/lo bf16 split ----------------
__global__ __launch_bounds__(256) void k_norms_split(const float* __restrict__ x,
                                                     float* __restrict__ sq,
                                                     ushort_t* __restrict__ xhi,
                                                     ushort_t* __restrict__ xlo) {
    int b = blockIdx.x;
    int tid = threadIdx.x;
    const float* xr = x + (size_t)b * D;
    ushort_t* hr = xhi + (size_t)b * D;
    ushort_t* lr = xlo + (size_t)b * D;
    float s = 0.f;
    #pragma unroll
    for (int m = 0; m < 16; ++m) {
        int e = m * 1024 + tid * 4;
        float4 v = *(const float4*)(xr + e);
        s += v.x * v.x + v.y * v.y + v.z * v.z + v.w * v.w;
        ushort4 h, l;
        h.x = f2bf(v.x); l.x = f2bf(v.x - bf2f(h.x));
        h.y = f2bf(v.y); l.y = f2bf(v.y - bf2f(h.y));
        h.z = f2bf(v.z); l.z = f2bf(v.z - bf2f(h.z));
        h.w = f2bf(v.w); l.w = f2bf(v.w - bf2f(h.w));
        *(ushort4*)(hr + e) = h;
        *(ushort4*)(lr + e) = l;
    }
    for (int off = 32; off; off >>= 1) s += __shfl_down(s, off, 64);
    __shared__ float red[4];
    if ((tid & 63) == 0) red[tid >> 6] = s;
    __syncthreads();
    if (tid == 0) sq[b] = red[0] + red[1] + red[2] + red[3];
}

// ---------------- kernel 2: GB = 0.5*Hi.Hi^T + Hi.Lo^T via MFMA ----------------
// XCD swizzle: ks = lin&7 pins each K-slice to one XCD's L2.
__global__ __launch_bounds__(256) void k_gram_mfma(const ushort_t* __restrict__ xhi,
                                                   const ushort_t* __restrict__ xlo,
                                                   float* __restrict__ Gp) {
    int lin = blockIdx.x + 8 * blockIdx.y + 64 * blockIdx.z;
    int ks = lin & 7, bi = (lin >> 3) & 7, bj = lin >> 6;
    int i0 = bi * 128, j0 = bj * 128;
    int tid = threadIdx.x;
    int w = tid >> 6, lane = tid & 63;
    int wm = w & 1, wn = w >> 1;
    int quad = lane >> 4, m16 = lane & 15;
    int srow = lane >> 2, sseg = lane & 3;

    __shared__ __align__(16) ushort_t Ahi_s[128 * 32];
    __shared__ __align__(16) ushort_t Bhi_s[128 * 32];
    __shared__ __align__(16) ushort_t Blo_s[128 * 32];

    f32x4 acc[4][4];
    #pragma unroll
    for (int ii = 0; ii < 4; ++ii)
        #pragma unroll
        for (int jj = 0; jj < 4; ++jj)
            acc[ii][jj] = (f32x4){0.f, 0.f, 0.f, 0.f};

    const size_t Abase = (size_t)i0 * D;
    const size_t Bbase = (size_t)j0 * D;

    for (int kb = 0; kb < KSUB / 32; ++kb) {
        int k0 = ks * KSUB + kb * 32;
        #pragma unroll
        for (int c = 0; c < 2; ++c) {
            int r = w * 32 + c * 16 + srow;
            size_t go = (size_t)r * D + k0 + sseg * 8;
            int lo = (w * 32 + c * 16) * 32;
            gload_lds16(xhi + Abase + go, &Ahi_s[lo]);
            gload_lds16(xhi + Bbase + go, &Bhi_s[lo]);
            gload_lds16(xlo + Bbase + go, &Blo_s[lo]);
        }
        __syncthreads();

        bf16x8 ah[4], bh[4], bl[4];
        #pragma unroll
        for (int ii = 0; ii < 4; ++ii) {
            int ar = wm * 64 + ii * 16 + m16;
            ah[ii] = *(const bf16x8*)&Ahi_s[ar * 32 + quad * 8];
        }
        #pragma unroll
        for (int jj = 0; jj < 4; ++jj) {
            int br = wn * 64 + jj * 16 + m16;
            bh[jj] = *(const bf16x8*)&Bhi_s[br * 32 + quad * 8];
            bl[jj] = *(const bf16x8*)&Blo_s[br * 32 + quad * 8];
        }
        #pragma unroll
        for (int ii = 0; ii < 4; ++ii) {
            bf16x8 ahh = bf8_half(ah[ii]);
            #pragma unroll
            for (int jj = 0; jj < 4; ++jj) {
                acc[ii][jj] = __builtin_amdgcn_mfma_f32_16x16x32_bf16(ahh, bh[jj], acc[ii][jj], 0, 0, 0);
                acc[ii][jj] = __builtin_amdgcn_mfma_f32_16x16x32_bf16(ah[ii], bl[jj], acc[ii][jj], 0, 0, 0);
            }
        }
        __syncthreads();
    }

    float* Gb = Gp + (size_t)ks * NSAMP * NSAMP;
    #pragma unroll
    for (int ii = 0; ii < 4; ++ii)
        #pragma unroll
        for (int jj = 0; jj < 4; ++jj) {
            int rg = i0 + wm * 64 + ii * 16 + quad * 4;
            int cg = j0 + wn * 64 + jj * 16 + m16;
            #pragma unroll
            for (int r = 0; r < 4; ++r)
                Gb[(size_t)(rg + r) * NSAMP + cg] = acc[ii][jj][r];
        }
}

// ---------------- kernel 2b: fold partials + symmetrize: G = Sum_p + Sum_p^T ----
// grid (16,16): 64x64 tile per block; transposed term staged via LDS so both
// the reads and the write are coalesced. k_select then reads only rows of G.
__global__ __launch_bounds__(256) void k_fold_sym(const float* __restrict__ Gp,
                                                  float* __restrict__ G) {
    int J = blockIdx.x, I = blockIdx.y;
    int t = threadIdx.x;
    int r = t >> 4, c4 = (t & 15) * 4;
    __shared__ float TJ[64][65];
    float4 sIJ[4];
    #pragma unroll
    for (int rr = 0; rr < 4; ++rr) {
        int row = rr * 16 + r;
        size_t oIJ = (size_t)(I * 64 + row) * NSAMP + J * 64 + c4;
        size_t oJI = (size_t)(J * 64 + row) * NSAMP + I * 64 + c4;
        float4 a = {0.f, 0.f, 0.f, 0.f}, bb = {0.f, 0.f, 0.f, 0.f};
        #pragma unroll
        for (int p = 0; p < KS; ++p) {
            float4 v = *(const float4*)(Gp + (size_t)p * NSAMP * NSAMP + oIJ);
            float4 w = *(const float4*)(Gp + (size_t)p * NSAMP * NSAMP + oJI);
            a.x += v.x; a.y += v.y; a.z += v.z; a.w += v.w;
            bb.x += w.x; bb.y += w.y; bb.z += w.z; bb.w += w.w;
        }
        sIJ[rr] = a;
        TJ[row][c4 + 0] = bb.x; TJ[row][c4 + 1] = bb.y;
        TJ[row][c4 + 2] = bb.z; TJ[row][c4 + 3] = bb.w;
    }
    __syncthreads();
    #pragma unroll
    for (int rr = 0; rr < 4; ++rr) {
        int row = rr * 16 + r;
        float4 v = sIJ[rr];
        v.x += TJ[c4 + 0][row]; v.y += TJ[c4 + 1][row];
        v.z += TJ[c4 + 2][row]; v.w += TJ[c4 + 3][row];
        *(float4*)(G + (size_t)(I * 64 + row) * NSAMP + J * 64 + c4) = v;
    }
}

// ---------------- kernel 3: hardest pos/neg + dsq init (row reads only) -----
__global__ void k_select(const float* __restrict__ G,
                         const float* __restrict__ sq, const int* __restrict__ tgt,
                         int* __restrict__ hp, int* __restrict__ hn,
                         float* __restrict__ dsq) {
    int i = blockIdx.x;
    int tid = threadIdx.x;
    float sqi = sq[i];
    int ti = tgt[i];
    float pv = -3.0e38f; int pj = 0x7FFFFFFF;
    float nv = 3.0e38f;  int nj = 0x7FFFFFFF;
    #pragma unroll
    for (int m = 0; m < 4; ++m) {
        int j = tid + 256 * m;
        float g = G[(size_t)i * NSAMP + j];
        float d2 = sqi + sq[j] - 2.f * g;
        float d = sqrtf(fmaxf(d2, 1e-12f));
        bool same = (tgt[j] == ti);
        float cp = same ? d : -1e30f;
        float cn = same ? 1e30f : d;
        if (cp > pv || (cp == pv && j < pj)) { pv = cp; pj = j; }
        if (cn < nv || (cn == nv && j < nj)) { nv = cn; nj = j; }
    }
    for (int off = 32; off; off >>= 1) {
        float opv = __shfl_down(pv, off, 64); int opj = __shfl_down(pj, off, 64);
        float onv = __shfl_down(nv, off, 64); int onj = __shfl_down(nj, off, 64);
        if (opv > pv || (opv == pv && opj < pj)) { pv = opv; pj = opj; }
        if (onv < nv || (onv == nv && onj < nj)) { nv = onv; nj = onj; }
    }
    __shared__ float spv[4], snv[4];
    __shared__ int spj[4], snj[4];
    if ((tid & 63) == 0) { int wv = tid >> 6; spv[wv] = pv; spj[wv] = pj; snv[wv] = nv; snj[wv] = nj; }
    __syncthreads();
    if (tid == 0) {
        for (int wv = 1; wv < 4; ++wv) {
            if (spv[wv] > pv || (spv[wv] == pv && spj[wv] < pj)) { pv = spv[wv]; pj = spj[wv]; }
            if (snv[wv] < nv || (snv[wv] == nv && snj[wv] < nj)) { nv = snv[wv]; nj = snj[wv]; }
        }
        hp[i] = pj; hn[i] = nj;
        // dsq = ||A||^2 init; k_dc adds (-2*Tr(A.M) + ||M||^2)
        dsq[i] = sqi; dsq[NSAMP + i] = sqi;
    }
}

// ---------------- kernel 4: DC align via MFMA, 32KB LDS ----------------
// grid (b=1024, which=2), 4 waves. O staged+transposed in place (32KB);
// P never touches LDS: after softmax each wave rebuilds its M-pass P-frags
// from C-layout registers via intra-wave shuffles among the 4 quads.
__global__ __launch_bounds__(256) void k_dc_mfma(const ushort_t* __restrict__ xhi,
                                                 const int* __restrict__ hp,
                                                 const int* __restrict__ hn,
                                                 float* __restrict__ dsq) {
    int b = blockIdx.x;
    int which = blockIdx.y;
    int oidx = (which == 0) ? hp[b] : hn[b];
    const ushort_t* Ag = xhi + (size_t)b * D;
    const ushort_t* Og = xhi + (size_t)oidx * D;

    __shared__ __align__(16) char smem[32768];   // O, then Ot in place

    int tid = threadIdx.x;
    int wv = tid >> 6, lane = tid & 63;
    int quad = lane >> 4, m16 = lane & 15;

    // A-frags from global (own rows per wave)
    bf16x8 af[2][4];
    #pragma unroll
    for (int tj2 = 0; tj2 < 2; ++tj2) {
        int r = (2 * wv + tj2) * 16 + m16;
        #pragma unroll
        for (int ks = 0; ks < 4; ++ks)
            af[tj2][ks] = *(const bf16x8*)(Ag + r * WH + ks * 32 + quad * 8);
    }

    // stage O into swizzled LDS
    uint4 stg[8];
    #pragma unroll
    for (int k = 0; k < 8; ++k)
        stg[k] = *(const uint4*)((const char*)Og + (size_t)(tid + 256 * k) * 16);
    #pragma unroll
    for (int k = 0; k < 8; ++k) {
        int g = tid + 256 * k;
        *(uint4*)(smem + lds_off(g >> 4, (g & 15) * 8)) = stg[k];
    }
    __syncthreads();   // B1: O staged

    // ---- S^T pass ----
    f32x4 accS[8][2];
    #pragma unroll
    for (int ti = 0; ti < 8; ++ti)
        #pragma unroll
        for (int tj2 = 0; tj2 < 2; ++tj2)
            accS[ti][tj2] = (f32x4){0.f, 0.f, 0.f, 0.f};
    #pragma unroll
    for (int ks = 0; ks < 4; ++ks) {
        bf16x8 of[8];
        #pragma unroll
        for (int ti = 0; ti < 8; ++ti)
            of[ti] = *(const bf16x8*)(smem + lds_off(ti * 16 + m16, (ks * 4 + quad) * 8));
        #pragma unroll
        for (int ti = 0; ti < 8; ++ti)
            #pragma unroll
            for (int tj2 = 0; tj2 < 2; ++tj2)
                accS[ti][tj2] = __builtin_amdgcn_mfma_f32_16x16x32_bf16(of[ti], af[tj2][ks], accS[ti][tj2], 0, 0, 0);
    }

    // transpose read phase (O still valid)
    int c0 = (tid & 31) * 4, h0 = (tid >> 5) * 16;
    uint4 trd[4][2];
    #pragma unroll
    for (int j = 0; j < 4; ++j)
        #pragma unroll
        for (int k = 0; k < 2; ++k)
            trd[j][k] = *(const uint4*)(smem + lds_off(c0 + j, h0 + 8 * k));
    __syncthreads();   // B2: all O reads done

    // transpose write: (c,h) -> (h,c) in place
    #pragma unroll
    for (int i = 0; i < 16; ++i) {
        uint v[4];
        #pragma unroll
        for (int j = 0; j < 4; ++j) {
            uint wo = ((const uint*)&trd[j][i >> 3])[(i >> 1) & 3];
            v[j] = (i & 1) ? (wo >> 16) : (wo & 0xffffu);
        }
        uint2 pk;
        pk.x = v[0] | (v[1] << 16);
        pk.y = v[2] | (v[3] << 16);
        *(uint2*)(smem + lds_off(h0 + i, c0)) = pk;
    }

    // ---- softmax over c + in-register P-frag build (fills the B2->B3 gap) ----
    // After softmax, lane(quad,m16) holds P[r=R0+m16][c=ti*16+quad*4+reg].
    // M-pass A-frag needs P[r][ks*32+quad*8+j] -> pure 4-quad permutation:
    //   pf[ks] uint k = shfl(Ep[2ks+(quad>>1)][k&1], ((2*quad+(k>>1))&3)*16+m16)
    float tpart = 0.f;
    bf16x8 pf[2][4];
    #pragma unroll
    for (int tj2 = 0; tj2 < 2; ++tj2) {
        float mx = -3.0e38f;
        #pragma unroll
        for (int ti = 0; ti < 8; ++ti)
            #pragma unroll
            for (int r = 0; r < 4; ++r) {
                float s = accS[ti][tj2][r] * SCALE;
                accS[ti][tj2][r] = s;
                mx = fmaxf(mx, s);
            }
        mx = fmaxf(mx, __shfl_xor(mx, 16, 64));
        mx = fmaxf(mx, __shfl_xor(mx, 32, 64));
        float sum = 0.f, tnum = 0.f;
        #pragma unroll
        for (int ti = 0; ti < 8; ++ti)
            #pragma unroll
            for (int r = 0; r < 4; ++r) {
                float s = accS[ti][tj2][r];
                float e = __expf(s - mx);
                accS[ti][tj2][r] = e;
                sum += e;
                tnum += s * e;
            }
        sum += __shfl_xor(sum, 16, 64);
        sum += __shfl_xor(sum, 32, 64);
        tnum += __shfl_xor(tnum, 16, 64);
        tnum += __shfl_xor(tnum, 32, 64);
        float inv = 1.f / sum;
        tpart += 0.25f * tnum * inv;       // all 4 quads add the full row sum

        // pack normalized bf16 pairs: Ep[ti][u] = P[c=ti*16+quad*4+2u | +2u+1]
        uint Ep[8][2];
        #pragma unroll
        for (int ti = 0; ti < 8; ++ti) {
            Ep[ti][0] = (uint)f2bf(accS[ti][tj2][0] * inv) |
                        ((uint)f2bf(accS[ti][tj2][1] * inv) << 16);
            Ep[ti][1] = (uint)f2bf(accS[ti][tj2][2] * inv) |
                        ((uint)f2bf(accS[ti][tj2][3] * inv) << 16);
        }
        int tih = quad >> 1;
        #pragma unroll
        for (int ks = 0; ks < 4; ++ks) {
            union { uint u[4]; bf16x8 v; } fr;
            #pragma unroll
            for (int k = 0; k < 4; ++k) {
                int src = (((quad << 1) + (k >> 1)) & 3) * 16 + m16;
                int a = __shfl((int)Ep[2 * ks + 0][k & 1], src, 64);
                int bsh = __shfl((int)Ep[2 * ks + 1][k & 1], src, 64);
                fr.u[k] = (uint)((tih == 0) ? a : bsh);
            }
            pf[tj2][ks] = fr.v;
        }
    }
    __syncthreads();   // B3: Ot complete

    // ---- M pass: M = P . O via MFMA(pf, Ot rows) ----
    f32x4 accM[2][8];
    #pragma unroll
    for (int tj2 = 0; tj2 < 2; ++tj2)
        #pragma unroll
        for (int tj = 0; tj < 8; ++tj)
            accM[tj2][tj] = (f32x4){0.f, 0.f, 0.f, 0.f};
    #pragma unroll
    for (int ks = 0; ks < 4; ++ks) {
        bf16x8 otf[8];
        #pragma unroll
        for (int tj = 0; tj < 8; ++tj)
            otf[tj] = *(const bf16x8*)(smem + lds_off(tj * 16 + m16, (ks * 4 + quad) * 8));
        #pragma unroll
        for (int tj2 = 0; tj2 < 2; ++tj2)
            #pragma unroll
            for (int tj = 0; tj < 8; ++tj)
                accM[tj2][tj] = __builtin_amdgcn_mfma_f32_16x16x32_bf16(pf[tj2][ks], otf[tj], accM[tj2][tj], 0, 0, 0);
    }

    float m2 = 0.f;
    #pragma unroll
    for (int tj2 = 0; tj2 < 2; ++tj2)
        #pragma unroll
        for (int tj = 0; tj < 8; ++tj)
            #pragma unroll
            for (int r = 0; r < 4; ++r) {
                float mvv = accM[tj2][tj][r];
                m2 += mvv * mvv;
            }
    float part = m2 - 2.f * RSCALE * tpart;
    for (int off = 32; off; off >>= 1) part += __shfl_down(part, off, 64);
    if (lane == 0) atomicAdd(&dsq[which * NSAMP + b], part);
}

// ---------------- kernel 5: final loss ----------------
__global__ void k_loss(const float* __restrict__ dsq, float* __restrict__ out) {
    int tid = threadIdx.x;
    float s = 0.f;
    #pragma unroll
    for (int m = 0; m < 4; ++m) {
        int b = tid + 256 * m;
        float ap = sqrtf(fmaxf(dsq[b], 0.f));
        float an = sqrtf(fmaxf(dsq[NSAMP + b], 0.f));
        s += fmaxf(ap - an + MARGIN, 0.f);
    }
    for (int off = 32; off; off >>= 1) s += __shfl_down(s, off, 64);
    __shared__ float red[4];
    if ((tid & 63) == 0) red[tid >> 6] = s;
    __syncthreads();
    if (tid == 0) out[0] = (red[0] + red[1] + red[2] + red[3]) * (1.f / NSAMP);
}

extern "C" void kernel_launch(void* const* d_in, const int* in_sizes, int n_in,
                              void* d_out, int out_size, void* d_ws, size_t ws_size,
                              hipStream_t stream) {
    const float* x = (const float*)d_in[0];
    const int* tgt = (const int*)d_in[1];
    float* out = (float*)d_out;
    char* ws = (char*)d_ws;

    float* Gp = (float*)ws;                                       // KS * 4 MB = 32 MB
    ushort_t* xhi = (ushort_t*)(ws + (size_t)32 * 1024 * 1024);   // 32 MB
    ushort_t* xlo = xhi + (size_t)NSAMP * D;                      // 32 MB (dead after gram)
    float* G = (float*)xlo;                                       // 4 MB, overlays xlo
    float* sq = (float*)(ws + (size_t)96 * 1024 * 1024);          // 4 KB
    float* dsq = sq + NSAMP;                                      // 8 KB
    int* hp = (int*)(dsq + 2 * NSAMP);                            // 4 KB
    int* hn = hp + NSAMP;                                         // 4 KB

    k_norms_split<<<NSAMP, 256, 0, stream>>>(x, sq, xhi, xlo);
    k_gram_mfma<<<dim3(8, 8, 8), 256, 0, stream>>>(xhi, xlo, Gp);
    k_fold_sym<<<dim3(16, 16), 256, 0, stream>>>(Gp, G);
    k_select<<<NSAMP, 256, 0, stream>>>(G, sq, tgt, hp, hn, dsq);
    k_dc_mfma<<<dim3(NSAMP, 2), 256, 0, stream>>>(xhi, hp, hn, dsq);
    k_loss<<<1, 256, 0, stream>>>(dsq, out);
}